// Round 17
// baseline (48.628 us; speedup 1.0000x reference)
//
#include <hip/hip_runtime.h>
#include <hip/hip_bf16.h>
#include <stdint.h>

typedef unsigned short u16t;
typedef float f32x4 __attribute__((ext_vector_type(4)));
typedef short bf16x8 __attribute__((ext_vector_type(8)));

#define SDIM 224

__device__ __forceinline__ float lo16(uint32_t w) { union { uint32_t u; float f; } v; v.u = w << 16; return v.f; }
__device__ __forceinline__ u16t bf1(float a) {
    union { __hip_bfloat16 h; u16t u; } c; c.h = __float2bfloat16(a); return c.u;
}
__device__ __forceinline__ uint32_t pk2(float a, float b) {
    union { __hip_bfloat162 h; uint32_t u; } c;
    c.h = __float22bfloat162_rn(make_float2(a, b));
    return c.u;
}

// ---------------------------------------------------------------------------
// Prep: pack GEMM B-operands, MFMA-frag order: buf[(kb*N+n)*8+j] = W[kb*8+j][n]
// psum k-mapping is H-MAJOR: k = h*8 + i  (one b128 psum write per lane).
//  wtA (K=544): k<512: h=k>>3,i=k&7 -> h2wA[h*512+i*64+n]; [512,520): h2bA;
//               [520,544): 0
//  wtB (K=544): k<512: h=k>>3,i=k&7 (i<6) -> h2wB[h*384+i*64+n] else 0;
//               [512,518): h2bB; [518,532): act_w; [532,544): 0
//  wt2: K=64, N=64 (hb1_w | hw2_w);  wtM: K=64, N=32 (hw1_w)
// ---------------------------------------------------------------------------
__global__ void prep_wt_kernel(const float* __restrict__ h2wA, const float* __restrict__ h2wB,
                               const float* __restrict__ h2bA, const float* __restrict__ h2bB,
                               const float* __restrict__ actw,
                               const float* __restrict__ hb1w, const float* __restrict__ hw2w,
                               const float* __restrict__ hw1w,
                               u16t* __restrict__ wtA, u16t* __restrict__ wtB,
                               u16t* __restrict__ wt2, u16t* __restrict__ wtM)
{
    const int t0 = blockIdx.x * 256 + threadIdx.x, stride = gridDim.x * 256;
    for (int e = t0; e < 34816; e += stride) {          // 68 kb * 64 n * 8 j
        int j = e & 7, n = (e >> 3) & 63, kb = e >> 9;
        int k = kb * 8 + j;
        float v = 0.f;
        if (k < 512)      { int h = k >> 3, i = k & 7; v = h2wA[h * 512 + i * 64 + n]; }
        else if (k < 520) v = h2bA[(k - 512) * 64 + n];
        wtA[e] = bf1(v);
    }
    for (int e = t0; e < 34816; e += stride) {
        int j = e & 7, n = (e >> 3) & 63, kb = e >> 9;
        int k = kb * 8 + j;
        float v = 0.f;
        if (k < 512)      { int h = k >> 3, i = k & 7; if (i < 6) v = h2wB[h * 384 + i * 64 + n]; }
        else if (k < 518) v = h2bB[(k - 512) * 64 + n];
        else if (k < 532) v = actw[(k - 518) * 64 + n];
        wtB[e] = bf1(v);
    }
    for (int e = t0; e < 4096; e += stride) {
        int j = e & 7, n = (e >> 3) & 63, kb = e >> 9;
        int k = kb * 8 + j;
        float v = (n < 32) ? hb1w[k * 32 + n] : hw2w[k * 32 + (n - 32)];
        wt2[e] = bf1(v);
    }
    for (int e = t0; e < 2048; e += stride) {
        int j = e & 7, n = (e >> 3) & 31, kb = e >> 8;
        wtM[e] = bf1(hw1w[(kb * 8 + j) * 32 + n]);
    }
}

// ---------------------------------------------------------------------------
// stage1 reading x DIRECTLY FROM GLOBAL (wave-uniform broadcast loads — off
// the LDS pipe). psum written h-major: ONE b128 per sample per lane.
// ---------------------------------------------------------------------------
template<int DIN>
__device__ __forceinline__ void stage1g(const float* __restrict__ xbase,  // + sample*SDIM
                                        u16t* __restrict__ ps,
                                        const float* __restrict__ s_h1w, float b1r,
                                        int wave, int lane)
{
    float w1r[DIN];
#pragma unroll
    for (int i = 0; i < DIN; ++i) w1r[i] = s_h1w[i * 64 + lane];
#pragma unroll 1
    for (int ss = 0; ss < 4; ++ss) {
        const int s = wave * 4 + ss;
        const float* xr = xbase + s * SDIM;
        float psv[8];
#pragma unroll
        for (int i = 0; i < 8; ++i) psv[i] = 0.f;
#pragma unroll
        for (int a = 0; a < 8; ++a) {
            float x[DIN];
            if constexpr (DIN == 8) {
                float4 v0 = *(const float4*)(xr + a * 8);
                float4 v1 = *(const float4*)(xr + a * 8 + 4);
                x[0] = v0.x; x[1] = v0.y; x[2] = v0.z; x[3] = v0.w;
                x[4] = v1.x; x[5] = v1.y; x[6] = v1.z; x[7] = v1.w;
            } else {
                float2 v0 = *(const float2*)(xr + a * 6);
                float2 v1 = *(const float2*)(xr + a * 6 + 2);
                float2 v2 = *(const float2*)(xr + a * 6 + 4);
                x[0] = v0.x; x[1] = v0.y; x[2] = v1.x; x[3] = v1.y; x[4] = v2.x; x[5] = v2.y;
            }
            float hacc = b1r;
#pragma unroll
            for (int i = 0; i < DIN; ++i) hacc += x[i] * w1r[i];
            hacc = fmaxf(hacc, 0.f);
#pragma unroll
            for (int i = 0; i < DIN; ++i) psv[i] += hacc * x[i];
        }
        uint4 p;
        p.x = pk2(psv[0], psv[1]);
        p.y = pk2(psv[2], psv[3]);
        p.z = pk2(psv[4], psv[5]);
        p.w = (DIN == 8) ? pk2(psv[6], psv[7]) : 0u;
        *(uint4*)&ps[s * 552 + lane * 8] = p;      // k = lane*8 + i (h-major)
    }
}

// ---------------------------------------------------------------------------
// Fused mixer: R14 barrier structure, LDS-op-minimized.
// ---------------------------------------------------------------------------
__global__ __launch_bounds__(256, 4)
void fused_mixer(const float* __restrict__ qvals, const float* __restrict__ states,
                 const float* __restrict__ hs,
                 const float* __restrict__ al_h1w, const float* __restrict__ al_h1b,
                 const float* __restrict__ en_h1w, const float* __restrict__ en_h1b,
                 const float* __restrict__ al_bias, const float* __restrict__ en_bias,
                 const float* __restrict__ act_b,
                 const float* __restrict__ hb1_b, const float* __restrict__ hw2_b,
                 const float* __restrict__ hw1_b, const float* __restrict__ hb2_w,
                 const float* __restrict__ hb2_b,
                 const u16t* __restrict__ wtA, const u16t* __restrict__ wtB,
                 const u16t* __restrict__ wt2, const u16t* __restrict__ wtM,
                 float* __restrict__ out)
{
    constexpr int KP = 552;
    __shared__ __align__(16) char  s_un[18432];    // psum (16*552*2=17664) then hs
    __shared__ float s_act[16][14];
    __shared__ __align__(16) u16t  s_se[16 * 72];
    __shared__ float s_b1w2[16][64];
    __shared__ float s_b2[16];
    __shared__ float s_q[128];
    __shared__ float s_h1wA[512], s_h1wB[384];
    __shared__ float s_h1bA[64], s_h1bB[64], s_bias3[64], s_hb2w[64];
    __shared__ float s_b1b[32], s_w2b[32], s_w1b[32];
    __shared__ float s_hb2bv;

    const int tid  = threadIdx.x;
    const int wave = tid >> 6;
    const int lane = tid & 63;
    const int lr = lane & 15, lg = lane >> 4;
    const int sbase = blockIdx.x * 16;
    const int o = wave * 16 + lr;                  // this thread's output column
    const float* xg = states + (size_t)sbase * SDIM;

    // ---- B0 staging (weights + act sums; no x staging) ----
    if (tid < 224) {
        int s = tid / 14, j = tid - (tid / 14) * 14;
        const float* ap = xg + s * SDIM + 112 + j;
        float t = 0.f;
#pragma unroll
        for (int a = 0; a < 8; ++a) t += ap[a * 14];
        s_act[s][j] = t;
    }
    for (int i = tid; i < 512; i += 256) s_h1wA[i] = al_h1w[i];
    for (int i = tid; i < 384; i += 256) s_h1wB[i] = en_h1w[i];
    if (tid < 64) {
        s_h1bA[tid] = al_h1b[tid]; s_h1bB[tid] = en_h1b[tid];
        s_bias3[tid] = al_bias[tid] + en_bias[tid] + act_b[tid];
        s_hb2w[tid] = hb2_w[tid];
    }
    if (tid >= 64 && tid < 96)   s_b1b[tid - 64] = hb1_b[tid - 64];
    if (tid >= 96 && tid < 128)  s_w2b[tid - 96] = hw2_b[tid - 96];
    if (tid >= 128 && tid < 160) s_w1b[tid - 128] = hw1_b[tid - 128];
    if (tid == 160) s_hb2bv = hb2_b[0];
    if (tid >= 128) s_q[tid - 128] = qvals[(size_t)sbase * 8 + (tid - 128)];
    __syncthreads();                               // B0

    u16t* ps = (u16t*)s_un;

    // ---- P1: stage1 A (global x) + xsumA rows + zero pad ----
    stage1g<8>(xg, ps, s_h1wA, s_h1bA[lane], wave, lane);
    if (tid < 128) {                               // xsumA rows k=512..519
        int s = tid >> 3, i = tid & 7;
        const float* xp = xg + s * SDIM + i;
        float t = 0.f;
#pragma unroll
        for (int a = 0; a < 8; ++a) t += xp[a * 8];
        ps[s * KP + 512 + i] = bf1(t);
    } else {                                       // zeros k=520..543
        int idx = tid - 128;
        for (int u = idx; u < 192; u += 128) {
            int s = u / 12, r = u - (u / 12) * 12;
            *(uint32_t*)&ps[s * KP + 520 + r * 2] = 0u;
        }
    }
    __syncthreads();                               // B1

    // ---- P2: GEMM A, M=16, N=16/wave, K=544 ----
    f32x4 accA = {0.f, 0.f, 0.f, 0.f};
    {
        const u16t* arow = ps + lr * KP + lg * 8;
        const bf16x8* wt8 = (const bf16x8*)wtA;
#pragma unroll 4
        for (int kk = 0; kk < 544; kk += 32) {
            bf16x8 av = *(const bf16x8*)(arow + kk);
            bf16x8 bv = wt8[((kk >> 3) + lg) * 64 + o];
            accA = __builtin_amdgcn_mfma_f32_16x16x32_bf16(av, bv, accA, 0, 0, 0);
        }
    }
    __syncthreads();                               // B2 (psumA free)

    // ---- P3: issue hs; stage1 B + ext rows ----
    float4 hsr[8];
    {
        const float4* hsv = (const float4*)(hs + (size_t)sbase * 512);
#pragma unroll
        for (int i = 0; i < 8; ++i) hsr[i] = hsv[i * 256 + tid];
    }
    stage1g<6>(xg + 64, ps, s_h1wB, s_h1bB[lane], wave, lane);
    if (tid < 96) {                                // xsumB rows k=512..517
        int s = tid / 6, i = tid - (tid / 6) * 6;
        const float* xp = xg + s * SDIM + 64 + i;
        float t = 0.f;
#pragma unroll
        for (int a = 0; a < 8; ++a) t += xp[a * 6];
        ps[s * KP + 512 + i] = bf1(t);
    } else {                                       // action rows k=518..531
        int idx = tid - 96;                        // 160 threads cover 224
        for (int u = idx; u < 224; u += 160) {
            int s = u / 14, j = u - (u / 14) * 14;
            ps[s * KP + 518 + j] = bf1(s_act[s][j]);
        }
    }
    if (tid < 96) {                                // zeros k=532..543
        int s = tid / 6, r = tid - (tid / 6) * 6;
        *(uint32_t*)&ps[s * KP + 532 + r * 2] = 0u;
    }
    __syncthreads();                               // B3

    // ---- P4: GEMM B K=544 + se epilogue ----
    {
        f32x4 accB = {0.f, 0.f, 0.f, 0.f};
        const u16t* arow = ps + lr * KP + lg * 8;
        const bf16x8* wt8 = (const bf16x8*)wtB;
#pragma unroll 4
        for (int kk = 0; kk < 544; kk += 32) {
            bf16x8 av = *(const bf16x8*)(arow + kk);
            bf16x8 bv = wt8[((kk >> 3) + lg) * 64 + o];
            accB = __builtin_amdgcn_mfma_f32_16x16x32_bf16(av, bv, accB, 0, 0, 0);
        }
#pragma unroll
        for (int j = 0; j < 4; ++j) {              // D rows lg*4+j = samples 0..15
            const int row = lg * 4 + j;
            float se = (accA[j] + accB[j]) * 0.125f + s_bias3[o];
            s_se[row * 72 + o] = bf1(fmaxf(se, 0.f));
        }
    }
    __syncthreads();                               // B4 (se ready, psumB dead)

    // ---- P5: hs regs -> LDS | b1w2 MFMA | b2 reduce ----
    u16t* s_hs = (u16t*)s_un;
    {
#pragma unroll
        for (int i = 0; i < 8; ++i) {
            const int idx = i * 256 + tid;
            const int row = idx >> 4, c4 = idx & 15;
            uint2 p;
            p.x = pk2(hsr[i].x, hsr[i].y);
            p.y = pk2(hsr[i].z, hsr[i].w);
            *(uint2*)&s_hs[row * 72 + c4 * 4] = p;
        }
    }
    {   // b1w2: M=16, K=64, N=16/wave
        f32x4 acc = {0.f, 0.f, 0.f, 0.f};
        const u16t* serow = &s_se[lr * 72 + lg * 8];
        const bf16x8* wt8 = (const bf16x8*)wt2;
#pragma unroll
        for (int ks = 0; ks < 2; ++ks) {
            bf16x8 av = *(const bf16x8*)(serow + ks * 32);
            bf16x8 bv = wt8[(ks * 4 + lg) * 64 + o];
            acc = __builtin_amdgcn_mfma_f32_16x16x32_bf16(av, bv, acc, 0, 0, 0);
        }
#pragma unroll
        for (int j = 0; j < 4; ++j) {
            const int row = lg * 4 + j;
            float v = acc[j] + ((o < 32) ? s_b1b[o] : s_w2b[o - 32]);
            if (o >= 32) v = fabsf(v);
            s_b1w2[row][o] = v;
        }
    }
    {   // b2: group (wave,lg) reduces sample smp over 64 cols
        const int smp = wave * 4 + lg;
        float p = 0.f;
#pragma unroll
        for (int c = 0; c < 4; ++c) {
            const int oo = c * 16 + lr;
            p += lo16((uint32_t)s_se[smp * 72 + oo]) * s_hb2w[oo];
        }
        p += __shfl_xor(p, 1); p += __shfl_xor(p, 2);
        p += __shfl_xor(p, 4); p += __shfl_xor(p, 8);
        if (lr == 0) s_b2[smp] = p + s_hb2bv;
    }
    __syncthreads();                               // B5

    // ---- P6: mix (z MFMA, softmax over 8 agents, q-mix, ELU, final dot) ----
    bf16x8 bfr[2][2];
    {
        const bf16x8* wtm8 = (const bf16x8*)wtM;
#pragma unroll
        for (int n = 0; n < 2; ++n)
#pragma unroll
            for (int ks = 0; ks < 2; ++ks)
                bfr[n][ks] = wtm8[(ks * 4 + lg) * 32 + n * 16 + lr];
    }
    const float zb0 = s_w1b[lr], zb1 = s_w1b[16 + lr];

    for (int t = wave * 2; t < wave * 2 + 2; ++t) {
        f32x4 d0 = {0.f,0.f,0.f,0.f}, d1 = {0.f,0.f,0.f,0.f};
#pragma unroll
        for (int ks = 0; ks < 2; ++ks) {
            bf16x8 av = *(const bf16x8*)&s_hs[(t * 16 + lr) * 72 + ks * 32 + lg * 8];
            d0 = __builtin_amdgcn_mfma_f32_16x16x32_bf16(av, bfr[0][ks], d0, 0, 0, 0);
            d1 = __builtin_amdgcn_mfma_f32_16x16x32_bf16(av, bfr[1][ks], d1, 0, 0, 0);
        }
        const int sloc = t * 2 + (lg >> 1);
        float z0[4], z1[4];
#pragma unroll
        for (int j = 0; j < 4; ++j) { z0[j] = d0[j] + zb0; z1[j] = d1[j] + zb1; }
        float m0 = fmaxf(fmaxf(z0[0], z0[1]), fmaxf(z0[2], z0[3]));
        float m1 = fmaxf(fmaxf(z1[0], z1[1]), fmaxf(z1[2], z1[3]));
        m0 = fmaxf(m0, __shfl_xor(m0, 16));
        m1 = fmaxf(m1, __shfl_xor(m1, 16));
        float qa[4];
        {
            float4 qv = *(const float4*)&s_q[sloc * 8 + (lg & 1) * 4];
            qa[0] = qv.x; qa[1] = qv.y; qa[2] = qv.z; qa[3] = qv.w;
        }
        float s0 = 0.f, s1 = 0.f, hp0 = 0.f, hp1 = 0.f;
#pragma unroll
        for (int j = 0; j < 4; ++j) {
            float e0 = __expf(z0[j] - m0), e1 = __expf(z1[j] - m1);
            s0 += e0; s1 += e1;
            hp0 += qa[j] * e0; hp1 += qa[j] * e1;
        }
        s0  += __shfl_xor(s0, 16);  s1  += __shfl_xor(s1, 16);
        hp0 += __shfl_xor(hp0, 16); hp1 += __shfl_xor(hp1, 16);

        const float b1_0 = s_b1w2[sloc][lr],      b1_1 = s_b1w2[sloc][16 + lr];
        const float w2_0 = s_b1w2[sloc][32 + lr], w2_1 = s_b1w2[sloc][48 + lr];
        float h0 = hp0 / s0 + b1_0; h0 = (h0 > 0.f) ? h0 : (__expf(h0) - 1.f);
        float h1 = hp1 / s1 + b1_1; h1 = (h1 > 0.f) ? h1 : (__expf(h1) - 1.f);
        float yp = h0 * w2_0 + h1 * w2_1;
        yp += __shfl_xor(yp, 1); yp += __shfl_xor(yp, 2);
        yp += __shfl_xor(yp, 4); yp += __shfl_xor(yp, 8);
        if (lr == 0 && (lg & 1) == 0) out[sbase + sloc] = yp + s_b2[sloc];
    }
}

extern "C" void kernel_launch(void* const* d_in, const int* in_sizes, int n_in,
                              void* d_out, int out_size, void* d_ws, size_t ws_size,
                              hipStream_t stream) {
    const float* qvals   = (const float*)d_in[0];
    const float* states  = (const float*)d_in[1];
    const float* hstates = (const float*)d_in[2];
    const float* hw1_w   = (const float*)d_in[3];
    const float* hw1_b   = (const float*)d_in[4];
    const float* en_h1w  = (const float*)d_in[5];
    const float* en_h1b  = (const float*)d_in[6];
    const float* en_h2w  = (const float*)d_in[7];
    const float* en_h2b  = (const float*)d_in[8];
    const float* en_bias = (const float*)d_in[9];
    const float* al_h1w  = (const float*)d_in[10];
    const float* al_h1b  = (const float*)d_in[11];
    const float* al_h2w  = (const float*)d_in[12];
    const float* al_h2b  = (const float*)d_in[13];
    const float* al_bias = (const float*)d_in[14];
    const float* act_w   = (const float*)d_in[15];
    const float* act_b   = (const float*)d_in[16];
    const float* hb1_w   = (const float*)d_in[17];
    const float* hb1_b   = (const float*)d_in[18];
    const float* hw2_w   = (const float*)d_in[19];
    const float* hw2_b   = (const float*)d_in[20];
    const float* hb2_w   = (const float*)d_in[21];
    const float* hb2_b   = (const float*)d_in[22];

    // ws (u16): wtA@0 (34816) | wtB@34816 (34816) | wt2@69632 (4096) | wtM@73728 (2048)
    u16t* wtA = (u16t*)d_ws;
    u16t* wtB = wtA + 34816;
    u16t* wt2 = wtA + 69632;
    u16t* wtM = wtA + 73728;

    prep_wt_kernel<<<64, 256, 0, stream>>>(al_h2w, en_h2w, al_h2b, en_h2b, act_w,
                                           hb1_w, hw2_w, hw1_w, wtA, wtB, wt2, wtM);
    fused_mixer<<<1024, 256, 0, stream>>>(qvals, states, hstates,
                                          al_h1w, al_h1b, en_h1w, en_h1b,
                                          al_bias, en_bias, act_b,
                                          hb1_b, hw2_b, hw1_b, hb2_w, hb2_b,
                                          wtA, wtB, wt2, wtM, (float*)d_out);
}